// Round 1
// baseline (1621.324 us; speedup 1.0000x reference)
//
#include <hip/hip_runtime.h>
#include <hip/hip_bf16.h>
#include <cstdint>
#include <cstddef>

#define NB 1024
#define DM 512
#define NH 8
#define HD 64
#define NT 81
#define O3 1536
#define NP 96

typedef __bf16 bf16x8 __attribute__((ext_vector_type(8)));
typedef float  f32x4  __attribute__((ext_vector_type(4)));
typedef unsigned short us8 __attribute__((ext_vector_type(8)));

__device__ __forceinline__ unsigned short f2bf(float f) {
    unsigned u = __builtin_bit_cast(unsigned, f);
    u += 0x7fffu + ((u >> 16) & 1u);          // round-to-nearest-even
    return (unsigned short)(u >> 16);
}
__device__ __forceinline__ float bf2f(unsigned short h) {
    unsigned u = ((unsigned)h) << 16;
    return __builtin_bit_cast(float, u);
}
__device__ __forceinline__ bf16x8 ld8(const unsigned short* p) {
    return __builtin_bit_cast(bf16x8, *(const us8*)p);
}

// ---------------- kernel 1: qkv_w fp32 -> bf16 ----------------
__global__ void conv_w(const float* __restrict__ w, unsigned short* __restrict__ wb, int n) {
    int i = blockIdx.x * 256 + threadIdx.x;
    if (i < n) wb[i] = f2bf(w[i]);
}

// ---------------- kernel 2: QKV projection GEMM ----------------
// qkv[b,o,n] = sum_c W[o,c] * x[b,c,n] + bias[o]  (+ rel term folded into K section)
// A = W (row-major [o][c]), B[k=c][n] = x[c][n] staged n-major (sXT).
#define OTILE 128
#define KC 32
#define SWS 40   // sW row stride (pad 32->40: conflict-free b128 frag reads)
#define SXS 40

__global__ __launch_bounds__(256) void qkv_gemm(
    const float* __restrict__ x,
    const unsigned short* __restrict__ wb,
    const float* __restrict__ bias,
    const float* __restrict__ relh,   // flat [H*64*9] : (h,d,0,j)
    const float* __restrict__ relw,   // flat [H*64*9] : (h,d,i,0)
    unsigned short* __restrict__ qkv)
{
    __shared__ unsigned short sW[OTILE * SWS];
    __shared__ unsigned short sXT[NP * SXS];

    const int tid  = threadIdx.x;
    const int lane = tid & 63;
    const int wv   = tid >> 6;
    const int b    = blockIdx.x / (O3 / OTILE);
    const int ot   = blockIdx.x % (O3 / OTILE);
    const int o0   = ot * OTILE;

    const int r16 = lane & 15;
    const int q8  = (lane >> 4) * 8;

    f32x4 acc[2][6];
    for (int i = 0; i < 2; ++i)
        for (int j = 0; j < 6; ++j)
            acc[i][j] = (f32x4){0.f, 0.f, 0.f, 0.f};

    const float* xb = x + (size_t)b * DM * NT;
    const int wr  = tid >> 2;        // 0..63 (W stage row)
    const int wc  = (tid & 3) * 8;   // 0,8,16,24
    const int xc  = tid >> 3;        // 0..31 (x stage row = c)
    const int xn0 = tid & 7;

    for (int kc = 0; kc < DM; kc += KC) {
        // stage W tile [128 x 32] bf16 (vectorized 16B)
        {
            us8 v0 = *(const us8*)(wb + (size_t)(o0 + wr) * DM + kc + wc);
            us8 v1 = *(const us8*)(wb + (size_t)(o0 + wr + 64) * DM + kc + wc);
            *(us8*)(&sW[wr * SWS + wc]) = v0;
            *(us8*)(&sW[(wr + 64) * SWS + wc]) = v1;
        }
        // stage x^T tile [96 x 32] (n-major), fp32 -> bf16 convert, pad n>=81 with 0
        {
            const float* xr = xb + (size_t)(kc + xc) * NT;
            #pragma unroll
            for (int j = 0; j < 12; ++j) {
                int n = xn0 + 8 * j;
                float v = (n < NT) ? xr[n] : 0.f;
                sXT[n * SXS + xc] = f2bf(v);
            }
        }
        __syncthreads();
        bf16x8 af0 = ld8(&sW[((wv * 2 + 0) * 16 + r16) * SWS + q8]);
        bf16x8 af1 = ld8(&sW[((wv * 2 + 1) * 16 + r16) * SWS + q8]);
        #pragma unroll
        for (int nt = 0; nt < 6; ++nt) {
            bf16x8 bfr = ld8(&sXT[(nt * 16 + r16) * SXS + q8]);
            acc[0][nt] = __builtin_amdgcn_mfma_f32_16x16x32_bf16(af0, bfr, acc[0][nt], 0, 0, 0);
            acc[1][nt] = __builtin_amdgcn_mfma_f32_16x16x32_bf16(af1, bfr, acc[1][nt], 0, 0, 0);
        }
        __syncthreads();
    }

    // epilogue: bias (+ rel for K section), store bf16
    unsigned short* qb = qkv + (size_t)b * O3 * NT;
    #pragma unroll
    for (int i = 0; i < 2; ++i) {
        int obase = o0 + (wv * 2 + i) * 16 + (lane >> 4) * 4;   // C/D row = quad*4+reg
        #pragma unroll
        for (int nt = 0; nt < 6; ++nt) {
            int n = nt * 16 + r16;                               // C/D col = lane&15
            if (n < NT) {
                #pragma unroll
                for (int r = 0; r < 4; ++r) {
                    int o = obase + r;
                    float v = acc[i][nt][r] + bias[o];
                    if (o >= DM && o < 2 * DM) {                 // K section: add r[h,d,m]
                        int oo = o - DM;                          // oo = h*64+d
                        v += relh[oo * 9 + (n % 9)] + relw[oo * 9 + (n / 9)];
                    }
                    qb[(size_t)o * NT + n] = f2bf(v);
                }
            }
        }
    }
}

// ---------------- kernel 3: attention per (b,h) ----------------
#define SQS 72    // sQT/sKT row stride (64 -> 72)
#define SVS 104   // sV/sPm row stride (96 -> 104)
#define SLS 97    // logits fp32 row stride (conflict-free softmax)
#define SPS 104

__global__ __launch_bounds__(256) void attn(
    const unsigned short* __restrict__ qkv,
    float* __restrict__ out)
{
    // LDS layout (bytes):
    //   [0,13312)      sV   64x104 bf16
    //   [13312,27136)  sQT  96x72  bf16   \ aliased by sL after logits MFMA
    //   [27136,40960)  sKT  96x72  bf16   /
    //   [13312,44740)  sL   81x97  fp32 (alias)
    //   [44752,64720)  sPm  96x104 bf16
    __shared__ __align__(16) unsigned char smem[64720];
    __shared__ float sRcp[NP];
    unsigned short* sV  = (unsigned short*)(smem);
    unsigned short* sQT = (unsigned short*)(smem + 13312);
    unsigned short* sKT = (unsigned short*)(smem + 27136);
    float*          sL  = (float*)(smem + 13312);
    unsigned short* sPm = (unsigned short*)(smem + 44752);

    const int tid  = threadIdx.x;
    const int lane = tid & 63;
    const int wv   = tid >> 6;
    const int b    = blockIdx.x >> 3;
    const int h    = blockIdx.x & 7;
    const int r16  = lane & 15;
    const int q8   = (lane >> 4) * 8;

    const unsigned short* qp = qkv + (size_t)b * O3 * NT + (size_t)(h * HD) * NT;
    const unsigned short* kp = qp + (size_t)DM * NT;
    const unsigned short* vp = qp + (size_t)(2 * DM) * NT;

    // stage V natural [d][m] (pad m with 0)
    for (int idx = tid; idx < HD * NP; idx += 256) {
        int d = idx / NP, m = idx - d * NP;
        sV[d * SVS + m] = (m < NT) ? vp[d * NT + m] : (unsigned short)0;
    }
    // stage q^T, k'^T: read coalesced over n, write transposed [n][d]
    for (int idx = tid; idx < HD * NP; idx += 256) {
        int d = idx / NP, n = idx - d * NP;
        unsigned short qv = (n < NT) ? qp[d * NT + n] : (unsigned short)0;
        unsigned short kv = (n < NT) ? kp[d * NT + n] : (unsigned short)0;
        sQT[n * SQS + d] = qv;
        sKT[n * SQS + d] = kv;
    }
    __syncthreads();

    // logits[n,m] = sum_d q^T[n,d] * k'[d,m] : 6x6 tiles of 16x16, K=64 (2 MFMA)
    f32x4 lacc[9];
    #pragma unroll
    for (int t = 0; t < 9; ++t) {
        int tile = wv * 9 + t;
        int ntile = tile / 6, mtile = tile - ntile * 6;
        f32x4 a = (f32x4){0.f, 0.f, 0.f, 0.f};
        bf16x8 qa0 = ld8(&sQT[(ntile * 16 + r16) * SQS + q8]);
        bf16x8 kb0 = ld8(&sKT[(mtile * 16 + r16) * SQS + q8]);
        a = __builtin_amdgcn_mfma_f32_16x16x32_bf16(qa0, kb0, a, 0, 0, 0);
        bf16x8 qa1 = ld8(&sQT[(ntile * 16 + r16) * SQS + 32 + q8]);
        bf16x8 kb1 = ld8(&sKT[(mtile * 16 + r16) * SQS + 32 + q8]);
        a = __builtin_amdgcn_mfma_f32_16x16x32_bf16(qa1, kb1, a, 0, 0, 0);
        lacc[t] = a;
    }
    __syncthreads();            // everyone done READING sQT/sKT before sL alias-write

    #pragma unroll
    for (int t = 0; t < 9; ++t) {
        int tile = wv * 9 + t;
        int ntile = tile / 6, mtile = tile - ntile * 6;
        int m  = mtile * 16 + r16;                 // C/D col
        int nb = ntile * 16 + (lane >> 4) * 4;     // C/D row
        #pragma unroll
        for (int r = 0; r < 4; ++r) {
            int n = nb + r;
            if (n < NT) sL[n * SLS + m] = lacc[t][r];
        }
    }
    __syncthreads();

    // softmax rows (one thread per row); store UNNORMALIZED exp as bf16,
    // fold 1/sum into PV epilogue via sRcp.
    if (tid < NP) {
        int n = tid;
        if (n < NT) {
            const float* row = &sL[n * SLS];
            float mx = -3.0e38f;
            for (int m = 0; m < NT; ++m) mx = fmaxf(mx, row[m]);
            float sum = 0.f;
            for (int m = 0; m < NT; ++m) {
                float e = exp2f((row[m] - mx) * 1.44269504088896f);
                unsigned short eb = f2bf(e);
                sPm[n * SPS + m] = eb;
                sum += bf2f(eb);
            }
            sRcp[n] = 1.0f / sum;
            for (int m = NT; m < NP; ++m) sPm[n * SPS + m] = 0;
        } else {
            for (int m = 0; m < NP; ++m) sPm[n * SPS + m] = 0;
        }
    }
    __syncthreads();

    // out^T[d,n] = sum_m v[d,m] * P[n,m] : A = v (natural), B = P^T (sPm n-major)
    f32x4 oacc[6];
    #pragma unroll
    for (int nt = 0; nt < 6; ++nt) {
        f32x4 a = (f32x4){0.f, 0.f, 0.f, 0.f};
        #pragma unroll
        for (int kt = 0; kt < 3; ++kt) {
            bf16x8 va = ld8(&sV[(wv * 16 + r16) * SVS + kt * 32 + q8]);
            bf16x8 pb = ld8(&sPm[(nt * 16 + r16) * SPS + kt * 32 + q8]);
            a = __builtin_amdgcn_mfma_f32_16x16x32_bf16(va, pb, a, 0, 0, 0);
        }
        oacc[nt] = a;
    }
    float* ob = out + (size_t)b * DM * NT + (size_t)(h * HD) * NT;
    #pragma unroll
    for (int nt = 0; nt < 6; ++nt) {
        int n = nt * 16 + r16;                     // C/D col = n
        if (n < NT) {
            float rs = sRcp[n];
            int db = wv * 16 + (lane >> 4) * 4;    // C/D row = d
            #pragma unroll
            for (int r = 0; r < 4; ++r)
                ob[(size_t)(db + r) * NT + n] = oacc[nt][r] * rs;
        }
    }
}

extern "C" void kernel_launch(void* const* d_in, const int* in_sizes, int n_in,
                              void* d_out, int out_size, void* d_ws, size_t ws_size,
                              hipStream_t stream) {
    const float* x     = (const float*)d_in[0];
    const float* qkv_w = (const float*)d_in[1];
    const float* qkv_b = (const float*)d_in[2];
    const float* rel_h = (const float*)d_in[3];
    const float* rel_w = (const float*)d_in[4];
    float* out = (float*)d_out;

    // ws layout: qkv bf16 [1024*1536*81] (255MB), then w_bf bf16 [1536*512]
    unsigned short* qkv = (unsigned short*)d_ws;
    unsigned short* wb  = qkv + (size_t)NB * O3 * NT;

    conv_w<<<dim3((O3 * DM + 255) / 256), dim3(256), 0, stream>>>(qkv_w, wb, O3 * DM);
    qkv_gemm<<<dim3(NB * (O3 / OTILE)), dim3(256), 0, stream>>>(x, wb, qkv_b, rel_h, rel_w, qkv);
    attn<<<dim3(NB * NH), dim3(256), 0, stream>>>(qkv, out);
}

// Round 2
// 975.162 us; speedup vs baseline: 1.6626x; 1.6626x over previous
//
#include <hip/hip_runtime.h>
#include <hip/hip_bf16.h>
#include <cstdint>
#include <cstddef>

#define NB 1024
#define DM 512
#define NH 8
#define HD 64
#define NT 81
#define O3 1536
#define NP 96

typedef __bf16 bf16x8 __attribute__((ext_vector_type(8)));
typedef float  f32x4  __attribute__((ext_vector_type(4)));
typedef unsigned short us8 __attribute__((ext_vector_type(8)));

__device__ __forceinline__ unsigned short f2bf(float f) {
    unsigned u = __builtin_bit_cast(unsigned, f);
    u += 0x7fffu + ((u >> 16) & 1u);          // round-to-nearest-even
    return (unsigned short)(u >> 16);
}
__device__ __forceinline__ float bf2f(unsigned short h) {
    unsigned u = ((unsigned)h) << 16;
    return __builtin_bit_cast(float, u);
}
__device__ __forceinline__ bf16x8 ld8(const unsigned short* p) {
    return __builtin_bit_cast(bf16x8, *(const us8*)p);
}
__device__ __forceinline__ void async16(void* lds, const void* g) {
    __builtin_amdgcn_global_load_lds(
        (const __attribute__((address_space(1))) void*)g,
        (__attribute__((address_space(3))) void*)lds, 16, 0, 0);
}

// ---------------- kernel 1: qkv_w fp32 -> bf16 ----------------
__global__ void conv_w(const float* __restrict__ w, unsigned short* __restrict__ wb, int n) {
    int i = blockIdx.x * 256 + threadIdx.x;
    if (i < n) wb[i] = f2bf(w[i]);
}

// ---------------- kernel 1b: x fp32 [b][c][n] -> xT bf16 [b][n=96][c=512] ----------------
// grid: NB * 8 (64-channel chunks). Pure transpose+convert, done ONCE (was 12x inside gemm).
__global__ __launch_bounds__(256) void transpose_x(
    const float* __restrict__ x, unsigned short* __restrict__ xT)
{
    __shared__ float sT[64][85];   // stride 85: 2-way (free) banks both phases
    const int tid = threadIdx.x;
    const int b  = blockIdx.x >> 3;
    const int c0 = (blockIdx.x & 7) * 64;
    const float* xb = x + ((size_t)b * DM + c0) * NT;

    const int nn = tid & 31, cc0 = tid >> 5;
    for (int i = 0; i < 8; ++i) {
        int cc = cc0 + i * 8;
        const float* xr = xb + (size_t)cc * NT;
        #pragma unroll
        for (int j = 0; j < 3; ++j) {
            int n = nn + 32 * j;
            if (n < NT) sT[cc][n] = xr[n];
        }
    }
    __syncthreads();

    const int ci = tid & 7, n0 = tid >> 3;    // ci: c-octet, n0: 0..31
    for (int i = 0; i < 3; ++i) {
        int n = n0 + 32 * i;                  // 0..95 (pad rows -> zeros)
        us8 v;
        #pragma unroll
        for (int j = 0; j < 8; ++j) {
            float f = (n < NT) ? sT[ci * 8 + j][n] : 0.f;
            v[j] = f2bf(f);
        }
        *(us8*)(xT + ((size_t)b * NP + n) * DM + c0 + ci * 8) = v;
    }
}

// ---------------- kernel 2a: QKV GEMM, pure global_load_lds staging ----------------
// Block tile: O=256 x N=96, KC=32, 16 ksteps. Wave: 4 o-subtiles x 6 n-tiles = 24 MFMA/kstep.
// Bit-identical accumulation vs round-1 (same MFMA shape, same ascending K order, same bf16 data).
#define OT 256
#define KC 32

__global__ __launch_bounds__(256) void qkv_gemm_a(
    const unsigned short* __restrict__ xT,
    const unsigned short* __restrict__ wb,
    const float* __restrict__ bias,
    const float* __restrict__ relh,
    const float* __restrict__ relw,
    unsigned short* __restrict__ qkv)
{
    __shared__ __align__(16) unsigned short sW[OT * KC];   // 16 KB, row-major [256][32]
    __shared__ __align__(16) unsigned short sX[NP * KC];   // 6 KB,  row-major [96][32]

    const int tid  = threadIdx.x;
    const int lane = tid & 63;
    const int wv   = tid >> 6;
    const int b    = blockIdx.x / 6;
    const int ot   = blockIdx.x % 6;
    const int o0   = ot * OT;
    const int r16  = lane & 15;
    const int q8   = (lane >> 4) * 8;

    f32x4 acc[4][6];
    #pragma unroll
    for (int i = 0; i < 4; ++i)
        #pragma unroll
        for (int j = 0; j < 6; ++j)
            acc[i][j] = (f32x4){0.f, 0.f, 0.f, 0.f};

    const unsigned short* xb = xT + (size_t)b * NP * DM;

    for (int kc = 0; kc < DM; kc += KC) {
        // stage W tile [256][32]: 1024 16B-chunks; chunk = row*4 + colblk
        #pragma unroll
        for (int i = 0; i < 4; ++i) {
            int ch  = i * 256 + wv * 64 + lane;
            int row = ch >> 2, cb = ch & 3;
            async16(&sW[(i * 256 + wv * 64) * 8],
                    wb + (size_t)(o0 + row) * DM + kc + cb * 8);
        }
        // stage X tile [96][32]: 384 chunks (iter0: all waves, iter1: waves 0-1)
        {
            int ch  = wv * 64 + lane;
            int row = ch >> 2, cb = ch & 3;
            async16(&sX[(wv * 64) * 8], xb + (size_t)row * DM + kc + cb * 8);
            if (wv < 2) {
                int ch2  = 256 + wv * 64 + lane;
                int row2 = ch2 >> 2, cb2 = ch2 & 3;
                async16(&sX[(256 + wv * 64) * 8], xb + (size_t)row2 * DM + kc + cb2 * 8);
            }
        }
        __syncthreads();
        bf16x8 af[4], bfr[6];
        #pragma unroll
        for (int i = 0; i < 4; ++i)
            af[i] = ld8(&sW[(wv * 64 + i * 16 + r16) * KC + q8]);
        #pragma unroll
        for (int nt = 0; nt < 6; ++nt)
            bfr[nt] = ld8(&sX[(nt * 16 + r16) * KC + q8]);
        #pragma unroll
        for (int i = 0; i < 4; ++i)
            #pragma unroll
            for (int nt = 0; nt < 6; ++nt)
                acc[i][nt] = __builtin_amdgcn_mfma_f32_16x16x32_bf16(af[i], bfr[nt], acc[i][nt], 0, 0, 0);
        __syncthreads();
    }

    unsigned short* qb = qkv + (size_t)b * O3 * NT;
    #pragma unroll
    for (int i = 0; i < 4; ++i) {
        int obase = o0 + (wv * 4 + i) * 16 + (lane >> 4) * 4;   // C/D row = quad*4+reg
        #pragma unroll
        for (int nt = 0; nt < 6; ++nt) {
            int n = nt * 16 + r16;                               // C/D col
            if (n < NT) {
                #pragma unroll
                for (int r = 0; r < 4; ++r) {
                    int o = obase + r;
                    float v = acc[i][nt][r] + bias[o];
                    if (o >= DM && o < 2 * DM) {                 // K section: fold rel
                        int oo = o - DM;
                        v += relh[oo * 9 + (n % 9)] + relw[oo * 9 + (n / 9)];
                    }
                    qb[(size_t)o * NT + n] = f2bf(v);
                }
            }
        }
    }
}

// ---------------- kernel 2b: fallback GEMM (round-1 verbatim, proven) ----------------
#define OTILE 128
#define SWS 40
#define SXS 40

__global__ __launch_bounds__(256) void qkv_gemm_fb(
    const float* __restrict__ x,
    const unsigned short* __restrict__ wb,
    const float* __restrict__ bias,
    const float* __restrict__ relh,
    const float* __restrict__ relw,
    unsigned short* __restrict__ qkv)
{
    __shared__ unsigned short sW[OTILE * SWS];
    __shared__ unsigned short sXT[NP * SXS];

    const int tid  = threadIdx.x;
    const int lane = tid & 63;
    const int wv   = tid >> 6;
    const int b    = blockIdx.x / (O3 / OTILE);
    const int ot   = blockIdx.x % (O3 / OTILE);
    const int o0   = ot * OTILE;
    const int r16 = lane & 15;
    const int q8  = (lane >> 4) * 8;

    f32x4 acc[2][6];
    for (int i = 0; i < 2; ++i)
        for (int j = 0; j < 6; ++j)
            acc[i][j] = (f32x4){0.f, 0.f, 0.f, 0.f};

    const float* xb = x + (size_t)b * DM * NT;
    const int wr  = tid >> 2;
    const int wc  = (tid & 3) * 8;
    const int xc  = tid >> 3;
    const int xn0 = tid & 7;

    for (int kc = 0; kc < DM; kc += 32) {
        {
            us8 v0 = *(const us8*)(wb + (size_t)(o0 + wr) * DM + kc + wc);
            us8 v1 = *(const us8*)(wb + (size_t)(o0 + wr + 64) * DM + kc + wc);
            *(us8*)(&sW[wr * SWS + wc]) = v0;
            *(us8*)(&sW[(wr + 64) * SWS + wc]) = v1;
        }
        {
            const float* xr = xb + (size_t)(kc + xc) * NT;
            #pragma unroll
            for (int j = 0; j < 12; ++j) {
                int n = xn0 + 8 * j;
                float v = (n < NT) ? xr[n] : 0.f;
                sXT[n * SXS + xc] = f2bf(v);
            }
        }
        __syncthreads();
        bf16x8 af0 = ld8(&sW[((wv * 2 + 0) * 16 + r16) * SWS + q8]);
        bf16x8 af1 = ld8(&sW[((wv * 2 + 1) * 16 + r16) * SWS + q8]);
        #pragma unroll
        for (int nt = 0; nt < 6; ++nt) {
            bf16x8 bfr = ld8(&sXT[(nt * 16 + r16) * SXS + q8]);
            acc[0][nt] = __builtin_amdgcn_mfma_f32_16x16x32_bf16(af0, bfr, acc[0][nt], 0, 0, 0);
            acc[1][nt] = __builtin_amdgcn_mfma_f32_16x16x32_bf16(af1, bfr, acc[1][nt], 0, 0, 0);
        }
        __syncthreads();
    }

    unsigned short* qb = qkv + (size_t)b * O3 * NT;
    #pragma unroll
    for (int i = 0; i < 2; ++i) {
        int obase = o0 + (wv * 2 + i) * 16 + (lane >> 4) * 4;
        #pragma unroll
        for (int nt = 0; nt < 6; ++nt) {
            int n = nt * 16 + r16;
            if (n < NT) {
                #pragma unroll
                for (int r = 0; r < 4; ++r) {
                    int o = obase + r;
                    float v = acc[i][nt][r] + bias[o];
                    if (o >= DM && o < 2 * DM) {
                        int oo = o - DM;
                        v += relh[oo * 9 + (n % 9)] + relw[oo * 9 + (n / 9)];
                    }
                    qb[(size_t)o * NT + n] = f2bf(v);
                }
            }
        }
    }
}

// ---------------- kernel 3: attention per (b,h) ----------------
#define SQS 72    // sQT/sKT row stride
#define SVS 104   // sV/sPm row stride
#define SLS 97    // logits fp32 row stride

__global__ __launch_bounds__(256) void attn(
    const unsigned short* __restrict__ qkv,
    float* __restrict__ out)
{
    __shared__ __align__(16) unsigned char smem[64720];
    __shared__ float sRcp[NP];
    unsigned short* sV  = (unsigned short*)(smem);
    unsigned short* sQT = (unsigned short*)(smem + 13312);
    unsigned short* sKT = (unsigned short*)(smem + 27136);
    float*          sL  = (float*)(smem + 13312);
    unsigned short* sPm = (unsigned short*)(smem + 44752);

    const int tid  = threadIdx.x;
    const int lane = tid & 63;
    const int wv   = tid >> 6;
    const int b    = blockIdx.x >> 3;
    const int h    = blockIdx.x & 7;
    const int r16  = lane & 15;
    const int q8   = (lane >> 4) * 8;

    const unsigned short* qp = qkv + (size_t)b * O3 * NT + (size_t)(h * HD) * NT;
    const unsigned short* kp = qp + (size_t)DM * NT;
    const unsigned short* vp = qp + (size_t)(2 * DM) * NT;

    // upfront zero of the whole P buffer (covers all pads; exp writes land later, barrier-separated)
    for (int idx = tid; idx < NP * 52; idx += 256) ((unsigned int*)sPm)[idx] = 0u;

    // stage V [d][m], pair-packed u32 writes
    for (int idx = tid; idx < HD * 52; idx += 256) {
        int d = idx / 52, m2 = idx - d * 52;
        int m0 = 2 * m2;
        unsigned e0 = (m0 < NT)     ? (unsigned)vp[d * NT + m0]     : 0u;
        unsigned e1 = (m0 + 1 < NT) ? (unsigned)vp[d * NT + m0 + 1] : 0u;
        ((unsigned int*)sV)[d * 52 + m2] = e0 | (e1 << 16);
    }
    // stage q^T, k'^T: coalesced reads over n, pair-packed (2 d per u32) transposed writes
    for (int idx = tid; idx < 32 * NP; idx += 256) {
        int d2 = idx / NP, n = idx - d2 * NP;
        unsigned q0 = 0, q1 = 0, k0 = 0, k1 = 0;
        if (n < NT) {
            q0 = qp[(2 * d2) * NT + n]; q1 = qp[(2 * d2 + 1) * NT + n];
            k0 = kp[(2 * d2) * NT + n]; k1 = kp[(2 * d2 + 1) * NT + n];
        }
        ((unsigned int*)sQT)[n * 36 + d2] = q0 | (q1 << 16);
        ((unsigned int*)sKT)[n * 36 + d2] = k0 | (k1 << 16);
    }
    __syncthreads();

    // logits[n,m]: 6x6 tiles of 16x16, K=64
    f32x4 lacc[9];
    #pragma unroll
    for (int t = 0; t < 9; ++t) {
        int tile = wv * 9 + t;
        int ntile = tile / 6, mtile = tile - ntile * 6;
        f32x4 a = (f32x4){0.f, 0.f, 0.f, 0.f};
        bf16x8 qa0 = ld8(&sQT[(ntile * 16 + r16) * SQS + q8]);
        bf16x8 kb0 = ld8(&sKT[(mtile * 16 + r16) * SQS + q8]);
        a = __builtin_amdgcn_mfma_f32_16x16x32_bf16(qa0, kb0, a, 0, 0, 0);
        bf16x8 qa1 = ld8(&sQT[(ntile * 16 + r16) * SQS + 32 + q8]);
        bf16x8 kb1 = ld8(&sKT[(mtile * 16 + r16) * SQS + 32 + q8]);
        a = __builtin_amdgcn_mfma_f32_16x16x32_bf16(qa1, kb1, a, 0, 0, 0);
        lacc[t] = a;
    }
    __syncthreads();            // reads of sQT/sKT done before sL alias-write

    #pragma unroll
    for (int t = 0; t < 9; ++t) {
        int tile = wv * 9 + t;
        int ntile = tile / 6, mtile = tile - ntile * 6;
        int m  = mtile * 16 + r16;
        int nb = ntile * 16 + (lane >> 4) * 4;
        #pragma unroll
        for (int r = 0; r < 4; ++r) {
            int n = nb + r;
            if (n < NT) sL[n * SLS + m] = lacc[t][r];
        }
    }
    __syncthreads();

    // softmax: 2 threads/row, shfl_xor(1) to combine; unnormalized exp -> bf16 P
    if (tid < 2 * NT) {
        int n = tid >> 1, p = tid & 1;
        int m0 = p ? 41 : 0, m1 = p ? NT : 41;
        const float* row = &sL[n * SLS];
        float mx = -3.0e38f;
        for (int m = m0; m < m1; ++m) mx = fmaxf(mx, row[m]);
        mx = fmaxf(mx, __shfl_xor(mx, 1));
        float s = 0.f;
        for (int m = m0; m < m1; ++m) {
            float e = exp2f((row[m] - mx) * 1.44269504088896f);
            unsigned short eb = f2bf(e);
            sPm[n * SVS + m] = eb;
            s += bf2f(eb);
        }
        s += __shfl_xor(s, 1);
        if (p == 0) sRcp[n] = 1.0f / s;
    }
    __syncthreads();

    // out^T[d,n] = sum_m v[d,m] * P[n,m]
    f32x4 oacc[6];
    #pragma unroll
    for (int nt = 0; nt < 6; ++nt) {
        f32x4 a = (f32x4){0.f, 0.f, 0.f, 0.f};
        #pragma unroll
        for (int kt = 0; kt < 3; ++kt) {
            bf16x8 va = ld8(&sV[(wv * 16 + r16) * SVS + kt * 32 + q8]);
            bf16x8 pb = ld8(&sPm[(nt * 16 + r16) * SVS + kt * 32 + q8]);
            a = __builtin_amdgcn_mfma_f32_16x16x32_bf16(va, pb, a, 0, 0, 0);
        }
        oacc[nt] = a;
    }
    float* ob = out + (size_t)b * DM * NT + (size_t)(h * HD) * NT;
    #pragma unroll
    for (int nt = 0; nt < 6; ++nt) {
        int n = nt * 16 + r16;
        if (n < NT) {
            float rs = sRcp[n];
            int db = wv * 16 + (lane >> 4) * 4;
            #pragma unroll
            for (int r = 0; r < 4; ++r)
                ob[(size_t)(db + r) * NT + n] = oacc[nt][r] * rs;
        }
    }
}

extern "C" void kernel_launch(void* const* d_in, const int* in_sizes, int n_in,
                              void* d_out, int out_size, void* d_ws, size_t ws_size,
                              hipStream_t stream) {
    const float* x     = (const float*)d_in[0];
    const float* qkv_w = (const float*)d_in[1];
    const float* qkv_b = (const float*)d_in[2];
    const float* rel_h = (const float*)d_in[3];
    const float* rel_w = (const float*)d_in[4];
    float* out = (float*)d_out;

    // ws layout: qkv bf16 [1024*1536*81] | wb bf16 [1536*512] | xT bf16 [1024*96*512]
    unsigned short* qkv = (unsigned short*)d_ws;
    unsigned short* wb  = qkv + (size_t)NB * O3 * NT;
    unsigned short* xT  = wb + (size_t)O3 * DM;
    size_t need = ((size_t)NB * O3 * NT + (size_t)O3 * DM + (size_t)NB * NP * DM) * 2;

    conv_w<<<dim3((O3 * DM + 255) / 256), dim3(256), 0, stream>>>(qkv_w, wb, O3 * DM);
    if (ws_size >= need) {
        transpose_x<<<dim3(NB * 8), dim3(256), 0, stream>>>(x, xT);
        qkv_gemm_a<<<dim3(NB * 6), dim3(256), 0, stream>>>(xT, wb, qkv_b, rel_h, rel_w, qkv);
    } else {
        qkv_gemm_fb<<<dim3(NB * 12), dim3(256), 0, stream>>>(x, wb, qkv_b, rel_h, rel_w, qkv);
    }
    attn<<<dim3(NB * NH), dim3(256), 0, stream>>>(qkv, out);
}